// Round 1
// baseline (274.611 us; speedup 1.0000x reference)
//
#include <hip/hip_runtime.h>

namespace {

constexpr int N = 4, T = 2048, L = 2048;
constexpr int DQIN = 32, DFEAT = 34, DQK = 64, DV = 64;
constexpr int TT = 32;   // t-rows per block in main kernel
constexpr int WSTR = 36; // padded stride (floats) for W tile [l][row]; 36*4=144B keeps 16B align, bank stride 4

// workspace layout (float offsets); total ~6.6 MB
constexpr int V_SZ = 3 * N * L * DV;
constexpr int X_SZ = 3 * N * L;
constexpr int A_SZ = 3 * N * T;

// ---------------- Kernel A: per-(n,t) scalars a,g for each modality ----------------
__global__ __launch_bounds__(256) void mm_prep_qk(
    const float* __restrict__ ref_data, const float* __restrict__ Wq,
    const float* __restrict__ Wk1, const float* __restrict__ bk1, const float* __restrict__ lt1,
    const float* __restrict__ Wk2, const float* __restrict__ bk2, const float* __restrict__ lt2,
    const float* __restrict__ Wk3, const float* __restrict__ bk3, const float* __restrict__ lt3,
    float* __restrict__ Aq, float* __restrict__ Gq) {
  __shared__ float sWq[DQIN * DQK];
  __shared__ float sWk[3][DQK];
  __shared__ float sbk[3][DQK];
  const int tid = threadIdx.x;
  for (int i = tid; i < DQIN * DQK; i += 256) sWq[i] = Wq[i];
  if (tid < DQK) {
    sWk[0][tid] = Wk1[tid]; sWk[1][tid] = Wk2[tid]; sWk[2][tid] = Wk3[tid];
    sbk[0][tid] = bk1[tid]; sbk[1][tid] = bk2[tid]; sbk[2][tid] = bk3[tid];
  }
  __syncthreads();
  const int idx = blockIdx.x * 256 + tid;  // n*T + t
  float x[DQIN];
  const float* rp = ref_data + idx * DQIN;
#pragma unroll
  for (int i = 0; i < DQIN; i++) x[i] = rp[i];
  float qr[DQK];
#pragma unroll
  for (int j = 0; j < DQK; j += 4) {
    float4 acc = make_float4(0.f, 0.f, 0.f, 0.f);
#pragma unroll
    for (int i = 0; i < DQIN; i++) {
      const float4 w = *(const float4*)&sWq[i * DQK + j];
      acc.x = fmaf(x[i], w.x, acc.x);
      acc.y = fmaf(x[i], w.y, acc.y);
      acc.z = fmaf(x[i], w.z, acc.z);
      acc.w = fmaf(x[i], w.w, acc.w);
    }
    qr[j] = acc.x; qr[j + 1] = acc.y; qr[j + 2] = acc.z; qr[j + 3] = acc.w;
  }
  // fold 1/sqrt(tau) into a and g so inner loop is just s = -(a - g*x)^2
  const float rs[3] = {__expf(-0.5f * lt1[0]), __expf(-0.5f * lt2[0]), __expf(-0.5f * lt3[0])};
#pragma unroll
  for (int m = 0; m < 3; m++) {
    float g = 0.f, h = 0.f;
#pragma unroll
    for (int j = 1; j < DQK; j++) {
      g = fmaf(qr[j], sWk[m][j - 1], g);
      h = fmaf(qr[j], sbk[m][j - 1], h);
    }
    g += sWk[m][DQK - 1];  // Q[64] = 1 term
    h += sbk[m][DQK - 1];
    Aq[m * (N * T) + idx] = (qr[0] - h) * rs[m];
    Gq[m * (N * T) + idx] = g * rs[m];
  }
}

// ---------------- Kernel B: V = data[:, :32] @ Wv + bv, and packed x (last feature) ----------------
__global__ __launch_bounds__(256) void mm_prep_v(
    const float* __restrict__ d1, const float* __restrict__ d2, const float* __restrict__ d3,
    const float* __restrict__ Wv1, const float* __restrict__ bv1,
    const float* __restrict__ Wv2, const float* __restrict__ bv2,
    const float* __restrict__ Wv3, const float* __restrict__ bv3,
    float* __restrict__ V, float* __restrict__ X) {
  __shared__ float sWv[32 * DV];
  __shared__ float sbv[DV];
  const int m = blockIdx.x / ((N * L) / 4);  // 2048 blocks per modality
  const float* dm = (m == 0) ? d1 : (m == 1 ? d2 : d3);
  const float* Wv = (m == 0) ? Wv1 : (m == 1 ? Wv2 : Wv3);
  const float* bv = (m == 0) ? bv1 : (m == 1 ? bv2 : bv3);
  const int tid = threadIdx.x;
  for (int i = tid; i < 32 * DV; i += 256) sWv[i] = Wv[i];
  if (tid < DV) sbv[tid] = bv[tid];
  __syncthreads();
  const int nl = (blockIdx.x % ((N * L) / 4)) * 4 + (tid >> 6);  // 0..N*L-1
  const int c = tid & 63;
  const float* dp = dm + nl * DFEAT;
  float acc = sbv[c];
#pragma unroll 8
  for (int i = 0; i < 32; i++) acc = fmaf(dp[i], sWv[i * DV + c], acc);
  const int row = m * (N * L) + nl;
  V[row * DV + c] = acc;
  if (c == 0) X[row] = dp[DFEAT - 1];
}

// ---------------- Kernel C: main attention ----------------
// grid: 3*N*(T/TT) = 768 blocks, 256 threads (4 waves). Wave rg owns rows rg*8..rg*8+7; lane = out dim.
__global__ __launch_bounds__(256) void mm_attn_main(
    const float* __restrict__ ref_t,
    const float* __restrict__ t1, const float* __restrict__ t2, const float* __restrict__ t3,
    const float* __restrict__ V, const float* __restrict__ X,
    const float* __restrict__ Aq, const float* __restrict__ Gq,
    float* __restrict__ out) {
  __shared__ float sW[64 * WSTR];
  __shared__ float sA[TT], sG[TT], sM[TT];
  __shared__ int sC[TT];

  const int b = blockIdx.x;
  const int tile = b % (T / TT);
  const int n = (b / (T / TT)) % N;
  const int m = b / ((T / TT) * N);
  const float* tml = ((m == 0) ? t1 : (m == 1 ? t2 : t3)) + n * L;

  const int tid = threadIdx.x;
  const int lane = tid & 63;
  const int rg = tid >> 6;
  const int t0 = tile * TT;
  const int mnT = (m * N + n) * T;
  const int mnL = (m * N + n) * L;

  if (tid < TT) {
    const int t = t0 + tid;
    const float rt = ref_t[n * T + t];
    int lo = 0, hi = L;
    while (lo < hi) {  // first l with t[l] > rt  (valid = prefix [0, lo))
      const int mid = (lo + hi) >> 1;
      if (tml[mid] <= rt) lo = mid + 1; else hi = mid;
    }
    sC[tid] = lo;
    sA[tid] = Aq[mnT + t];
    sG[tid] = Gq[mnT + t];
    sM[tid] = 0.f;  // max of S*mask is exactly 0 whenever c < L (all s <= 0)
  }
  __syncthreads();
  const int cmax = sC[TT - 1];  // c_t monotone in t

  // max pass: only rows with c == L need a true running max (else denom >= 1 guaranteed)
  if (cmax == L) {
    float a8[8], g8[8], mx[8];
    int c8[8];
#pragma unroll
    for (int r = 0; r < 8; r++) {
      const int rr = rg * 8 + r;
      a8[r] = sA[rr]; g8[r] = sG[rr]; c8[r] = sC[rr];
      mx[r] = -1e30f;
    }
    for (int base = 0; base < L; base += 64) {
      const float xl = X[mnL + base + lane];
#pragma unroll
      for (int r = 0; r < 8; r++) {
        const float d = fmaf(-g8[r], xl, a8[r]);
        mx[r] = fmaxf(mx[r], -d * d);
      }
    }
#pragma unroll
    for (int r = 0; r < 8; r++) {
      float v = mx[r];
      for (int off = 32; off; off >>= 1) v = fmaxf(v, __shfl_xor(v, off, 64));
      if (lane == 0 && c8[r] == L) sM[rg * 8 + r] = v;
    }
  }
  __syncthreads();

  float a8[8], g8[8], M8[8], y[8], z8[8];
  int c8[8];
#pragma unroll
  for (int r = 0; r < 8; r++) {
    const int rr = rg * 8 + r;
    a8[r] = sA[rr]; g8[r] = sG[rr]; c8[r] = sC[rr]; M8[r] = sM[rr];
    y[r] = 0.f; z8[r] = 0.f;
  }

  const int nchunks = (cmax + 63) >> 6;
  for (int ch = 0; ch < nchunks; ch++) {
    const int base = ch << 6;
    // phase A: thread (lane, rg) computes w[row][l=base+lane] for its 8 rows
    const float xl = X[mnL + base + lane];
    const int l = base + lane;
#pragma unroll
    for (int r = 0; r < 8; r++) {
      const float d = fmaf(-g8[r], xl, a8[r]);
      float w = __expf(fmaf(-d, d, -M8[r]));  // exp(s - M), s = -d^2
      w = (l < c8[r]) ? w : 0.f;
      z8[r] += w;
      sW[lane * WSTR + rg * 8 + r] = w;
    }
    __syncthreads();
    // phase B: PV. lane = dim c; w broadcast-read from LDS as float4 pairs.
    const float* Vp = V + (mnL + base) * DV + lane;
    const int lim = min(64, cmax - base);
    if (lim == 64) {
#pragma unroll 8
      for (int li = 0; li < 64; li++) {
        const float v = Vp[li * DV];
        const float4 w0 = *(const float4*)&sW[li * WSTR + rg * 8];
        const float4 w1 = *(const float4*)&sW[li * WSTR + rg * 8 + 4];
        y[0] = fmaf(w0.x, v, y[0]); y[1] = fmaf(w0.y, v, y[1]);
        y[2] = fmaf(w0.z, v, y[2]); y[3] = fmaf(w0.w, v, y[3]);
        y[4] = fmaf(w1.x, v, y[4]); y[5] = fmaf(w1.y, v, y[5]);
        y[6] = fmaf(w1.z, v, y[6]); y[7] = fmaf(w1.w, v, y[7]);
      }
    } else {
      for (int li = 0; li < lim; li++) {
        const float v = Vp[li * DV];
        const float4 w0 = *(const float4*)&sW[li * WSTR + rg * 8];
        const float4 w1 = *(const float4*)&sW[li * WSTR + rg * 8 + 4];
        y[0] = fmaf(w0.x, v, y[0]); y[1] = fmaf(w0.y, v, y[1]);
        y[2] = fmaf(w0.z, v, y[2]); y[3] = fmaf(w0.w, v, y[3]);
        y[4] = fmaf(w1.x, v, y[4]); y[5] = fmaf(w1.y, v, y[5]);
        y[6] = fmaf(w1.z, v, y[6]); y[7] = fmaf(w1.w, v, y[7]);
      }
    }
    __syncthreads();
  }

  // finalize: Z = sum(w) + (L - c) * exp(-M); all lanes get Z via butterfly
#pragma unroll
  for (int r = 0; r < 8; r++) {
    float z = z8[r];
    for (int off = 32; off; off >>= 1) z += __shfl_xor(z, off, 64);
    z += (float)(L - c8[r]) * __expf(-M8[r]);
    const int t = t0 + rg * 8 + r;
    out[(mnT + t) * DV + lane] = y[r] / z;
  }
}

}  // namespace

extern "C" void kernel_launch(void* const* d_in, const int* in_sizes, int n_in,
                              void* d_out, int out_size, void* d_ws, size_t ws_size,
                              hipStream_t stream) {
  const float* ref_data = (const float*)d_in[0];
  const float* ref_t = (const float*)d_in[1];
  const float* m1_data = (const float*)d_in[2];
  const float* m1_t = (const float*)d_in[3];
  const float* m2_data = (const float*)d_in[4];
  const float* m2_t = (const float*)d_in[5];
  const float* m3_data = (const float*)d_in[6];
  const float* m3_t = (const float*)d_in[7];
  const float* Wq = (const float*)d_in[8];
  const float* Wk1 = (const float*)d_in[9];
  const float* bk1 = (const float*)d_in[10];
  const float* Wv1 = (const float*)d_in[11];
  const float* bv1 = (const float*)d_in[12];
  const float* lt1 = (const float*)d_in[13];
  const float* Wk2 = (const float*)d_in[14];
  const float* bk2 = (const float*)d_in[15];
  const float* Wv2 = (const float*)d_in[16];
  const float* bv2 = (const float*)d_in[17];
  const float* lt2 = (const float*)d_in[18];
  const float* Wk3 = (const float*)d_in[19];
  const float* bk3 = (const float*)d_in[20];
  const float* Wv3 = (const float*)d_in[21];
  const float* bv3 = (const float*)d_in[22];
  const float* lt3 = (const float*)d_in[23];

  float* ws = (float*)d_ws;
  float* Vw = ws;                 // 3*N*L*DV
  float* Xw = Vw + V_SZ;          // 3*N*L
  float* Aq = Xw + X_SZ;          // 3*N*T
  float* Gq = Aq + A_SZ;          // 3*N*T

  mm_prep_qk<<<dim3((N * T) / 256), dim3(256), 0, stream>>>(
      ref_data, Wq, Wk1, bk1, lt1, Wk2, bk2, lt2, Wk3, bk3, lt3, Aq, Gq);
  mm_prep_v<<<dim3((3 * N * L) / 4), dim3(256), 0, stream>>>(
      m1_data, m2_data, m3_data, Wv1, bv1, Wv2, bv2, Wv3, bv3, Vw, Xw);
  mm_attn_main<<<dim3(3 * N * (T / TT)), dim3(256), 0, stream>>>(
      ref_t, m1_t, m2_t, m3_t, Vw, Xw, Aq, Gq, (float*)d_out);
}

// Round 2
// 271.846 us; speedup vs baseline: 1.0102x; 1.0102x over previous
//
#include <hip/hip_runtime.h>

namespace {

constexpr int N = 4, T = 2048, L = 2048;
constexpr int DQIN = 32, DFEAT = 34, DQK = 64, DV = 64;
constexpr int TT = 32;    // t-rows per block in main kernel
constexpr int WSTR = 36;  // padded stride (floats) for W tile [l][row]; keeps 16B align
constexpr int SPLIT = 4;  // l-dimension split
constexpr int LSEG = L / SPLIT;  // 512

// workspace layout (float offsets)
constexpr int V_SZ = 3 * N * L * DV;   // 1.57M
constexpr int X_SZ = 3 * N * L;        // 24576
constexpr int A_SZ = 3 * N * T;        // 24576
constexpr int Y_SZ = 3 * N * T * DV;   // 1.57M
constexpr int Z_SZ = 3 * N * T;        // 24576

// ---------------- Kernel A: per-(n,t) scalars a,g + valid-prefix c for each modality ----------------
__global__ __launch_bounds__(256) void mm_prep_qk(
    const float* __restrict__ ref_data, const float* __restrict__ ref_t,
    const float* __restrict__ t1, const float* __restrict__ t2, const float* __restrict__ t3,
    const float* __restrict__ Wq,
    const float* __restrict__ Wk1, const float* __restrict__ bk1, const float* __restrict__ lt1,
    const float* __restrict__ Wk2, const float* __restrict__ bk2, const float* __restrict__ lt2,
    const float* __restrict__ Wk3, const float* __restrict__ bk3, const float* __restrict__ lt3,
    float* __restrict__ Aq, float* __restrict__ Gq, int* __restrict__ Cq) {
  __shared__ float sWq[DQIN * DQK];
  __shared__ float sWk[3][DQK];
  __shared__ float sbk[3][DQK];
  const int tid = threadIdx.x;
  for (int i = tid; i < DQIN * DQK; i += 256) sWq[i] = Wq[i];
  if (tid < DQK) {
    sWk[0][tid] = Wk1[tid]; sWk[1][tid] = Wk2[tid]; sWk[2][tid] = Wk3[tid];
    sbk[0][tid] = bk1[tid]; sbk[1][tid] = bk2[tid]; sbk[2][tid] = bk3[tid];
  }
  __syncthreads();
  const int idx = blockIdx.x * 256 + tid;  // n*T + t
  const int n = idx / T;
  float x[DQIN];
  const float* rp = ref_data + idx * DQIN;
#pragma unroll
  for (int i = 0; i < DQIN; i++) x[i] = rp[i];
  float qr[DQK];
#pragma unroll
  for (int j = 0; j < DQK; j += 4) {
    float4 acc = make_float4(0.f, 0.f, 0.f, 0.f);
#pragma unroll
    for (int i = 0; i < DQIN; i++) {
      const float4 w = *(const float4*)&sWq[i * DQK + j];
      acc.x = fmaf(x[i], w.x, acc.x);
      acc.y = fmaf(x[i], w.y, acc.y);
      acc.z = fmaf(x[i], w.z, acc.z);
      acc.w = fmaf(x[i], w.w, acc.w);
    }
    qr[j] = acc.x; qr[j + 1] = acc.y; qr[j + 2] = acc.z; qr[j + 3] = acc.w;
  }
  // fold 1/sqrt(tau) into a and g so inner loop is just s = -(a - g*x)^2
  const float rs[3] = {__expf(-0.5f * lt1[0]), __expf(-0.5f * lt2[0]), __expf(-0.5f * lt3[0])};
  const float rt = ref_t[idx];
#pragma unroll
  for (int m = 0; m < 3; m++) {
    float g = 0.f, h = 0.f;
#pragma unroll
    for (int j = 1; j < DQK; j++) {
      g = fmaf(qr[j], sWk[m][j - 1], g);
      h = fmaf(qr[j], sbk[m][j - 1], h);
    }
    g += sWk[m][DQK - 1];  // Q[64] = 1 term
    h += sbk[m][DQK - 1];
    Aq[m * (N * T) + idx] = (qr[0] - h) * rs[m];
    Gq[m * (N * T) + idx] = g * rs[m];
    // binary search: c = count of l with tml[l] <= rt
    const float* tml = ((m == 0) ? t1 : (m == 1 ? t2 : t3)) + n * L;
    int lo = 0, hi = L;
    while (lo < hi) {
      const int mid = (lo + hi) >> 1;
      if (tml[mid] <= rt) lo = mid + 1; else hi = mid;
    }
    Cq[m * (N * T) + idx] = lo;
  }
}

// ---------------- Kernel B: V = data[:, :32] @ Wv + bv, and packed x (last feature) ----------------
__global__ __launch_bounds__(256) void mm_prep_v(
    const float* __restrict__ d1, const float* __restrict__ d2, const float* __restrict__ d3,
    const float* __restrict__ Wv1, const float* __restrict__ bv1,
    const float* __restrict__ Wv2, const float* __restrict__ bv2,
    const float* __restrict__ Wv3, const float* __restrict__ bv3,
    float* __restrict__ V, float* __restrict__ X) {
  __shared__ float sWv[32 * DV];
  __shared__ float sbv[DV];
  const int m = blockIdx.x / ((N * L) / 4);
  const float* dm = (m == 0) ? d1 : (m == 1 ? d2 : d3);
  const float* Wv = (m == 0) ? Wv1 : (m == 1 ? Wv2 : Wv3);
  const float* bv = (m == 0) ? bv1 : (m == 1 ? bv2 : bv3);
  const int tid = threadIdx.x;
  for (int i = tid; i < 32 * DV; i += 256) sWv[i] = Wv[i];
  if (tid < DV) sbv[tid] = bv[tid];
  __syncthreads();
  const int nl = (blockIdx.x % ((N * L) / 4)) * 4 + (tid >> 6);
  const int c = tid & 63;
  const float* dp = dm + nl * DFEAT;
  float acc = sbv[c];
#pragma unroll 8
  for (int i = 0; i < 32; i++) acc = fmaf(dp[i], sWv[i * DV + c], acc);
  const int row = m * (N * L) + nl;
  V[row * DV + c] = acc;
  if (c == 0) X[row] = dp[DFEAT - 1];
}

// ---------------- Kernel C: main attention (l-split, atomic partial accumulation) ----------------
// grid: 3*N*(T/TT)*SPLIT blocks, 256 threads (4 waves). Wave rg owns rows rg*8..rg*8+7; lane = out dim.
__global__ __launch_bounds__(256) void mm_attn_main(
    const float* __restrict__ V, const float* __restrict__ X,
    const float* __restrict__ Aq, const float* __restrict__ Gq, const int* __restrict__ Cq,
    float* __restrict__ Yacc, float* __restrict__ Zacc) {
  __shared__ float sW[2][64 * WSTR];
  __shared__ float sA[TT], sG[TT];
  __shared__ int sC[TT];

  const int b = blockIdx.x;
  const int seg = b & (SPLIT - 1);
  const int bt = b >> 2;              // (m*N+n)*(T/TT) + tile
  const int tile = bt % (T / TT);
  const int mn = bt / (T / TT);       // m*N + n
  const int t0 = tile * TT;
  const int mnT = mn * T;
  const int mnL = mn * L;

  const int tid = threadIdx.x;
  const int lane = tid & 63;
  const int rg = tid >> 6;

  const int cmax = Cq[mnT + t0 + TT - 1];  // c_t monotone in t
  const int lBeg = seg * LSEG;
  if (lBeg >= cmax) return;  // nothing in this segment for any row of the tile

  if (tid < TT) {
    sA[tid] = Aq[mnT + t0 + tid];
    sG[tid] = Gq[mnT + t0 + tid];
    sC[tid] = Cq[mnT + t0 + tid];
  }
  __syncthreads();

  float a8[8], g8[8], y[8], z8[8];
  int c8[8];
#pragma unroll
  for (int r = 0; r < 8; r++) {
    const int rr = rg * 8 + r;
    a8[r] = sA[rr]; g8[r] = sG[rr]; c8[r] = sC[rr];
    y[r] = 0.f; z8[r] = 0.f;
  }

  const int lEnd = min(lBeg + LSEG, cmax);
  const int nch = (lEnd - lBeg + 63) >> 6;

  // prologue: weights for chunk 0 into buffer 0
  {
    const int l = lBeg + lane;
    const float xl = X[mnL + l];
#pragma unroll
    for (int r = 0; r < 8; r++) {
      const float d = fmaf(-g8[r], xl, a8[r]);
      float w = __expf(-d * d);
      w = (l < c8[r]) ? w : 0.f;
      z8[r] += w;
      sW[0][lane * WSTR + rg * 8 + r] = w;
    }
  }
  __syncthreads();

  for (int ch = 0; ch < nch; ch++) {
    const int base = lBeg + (ch << 6);
    // phase A for chunk ch+1 into the other buffer (no barrier needed: buffer disjoint)
    if (ch + 1 < nch) {
      const int l = base + 64 + lane;
      const float xl = X[mnL + l];
#pragma unroll
      for (int r = 0; r < 8; r++) {
        const float d = fmaf(-g8[r], xl, a8[r]);
        float w = __expf(-d * d);
        w = (l < c8[r]) ? w : 0.f;
        z8[r] += w;
        sW[(ch + 1) & 1][lane * WSTR + rg * 8 + r] = w;
      }
    }
    // phase B: PV on chunk ch. lane = dim; w broadcast-read from LDS as float4 pairs.
    const float* Vp = V + (mnL + base) * DV + lane;
    const float* wp = &sW[ch & 1][rg * 8];
    const int lim = min(64, lEnd - base);
    if (lim == 64) {
#pragma unroll 8
      for (int li = 0; li < 64; li++) {
        const float v = Vp[li * DV];
        const float4 w0 = *(const float4*)&wp[li * WSTR];
        const float4 w1 = *(const float4*)&wp[li * WSTR + 4];
        y[0] = fmaf(w0.x, v, y[0]); y[1] = fmaf(w0.y, v, y[1]);
        y[2] = fmaf(w0.z, v, y[2]); y[3] = fmaf(w0.w, v, y[3]);
        y[4] = fmaf(w1.x, v, y[4]); y[5] = fmaf(w1.y, v, y[5]);
        y[6] = fmaf(w1.z, v, y[6]); y[7] = fmaf(w1.w, v, y[7]);
      }
    } else {
      for (int li = 0; li < lim; li++) {
        const float v = Vp[li * DV];
        const float4 w0 = *(const float4*)&wp[li * WSTR];
        const float4 w1 = *(const float4*)&wp[li * WSTR + 4];
        y[0] = fmaf(w0.x, v, y[0]); y[1] = fmaf(w0.y, v, y[1]);
        y[2] = fmaf(w0.z, v, y[2]); y[3] = fmaf(w0.w, v, y[3]);
        y[4] = fmaf(w1.x, v, y[4]); y[5] = fmaf(w1.y, v, y[5]);
        y[6] = fmaf(w1.z, v, y[6]); y[7] = fmaf(w1.w, v, y[7]);
      }
    }
    __syncthreads();
  }

  // epilogue: butterfly-reduce z, atomically accumulate partials.
#pragma unroll
  for (int r = 0; r < 8; r++) {
    if (c8[r] <= lBeg) continue;  // this row has no weight in this segment
    float z = z8[r];
    for (int off = 32; off; off >>= 1) z += __shfl_xor(z, off, 64);
    const int t = t0 + rg * 8 + r;
    unsafeAtomicAdd(&Yacc[(mnT + t) * DV + lane], y[r]);
    if (lane == 0) unsafeAtomicAdd(&Zacc[mnT + t], z);
  }
}

// ---------------- Kernel D: finalize out = Y / (Z + (L - c)) ----------------
__global__ __launch_bounds__(256) void mm_finalize(
    const float* __restrict__ Yacc, const float* __restrict__ Zacc,
    const int* __restrict__ Cq, float* __restrict__ out) {
  const int i = blockIdx.x * 256 + threadIdx.x;  // over 3*N*T*DV
  const int row = i >> 6;
  const float Z = Zacc[row] + (float)(L - Cq[row]);
  out[i] = Yacc[i] / Z;
}

}  // namespace

extern "C" void kernel_launch(void* const* d_in, const int* in_sizes, int n_in,
                              void* d_out, int out_size, void* d_ws, size_t ws_size,
                              hipStream_t stream) {
  const float* ref_data = (const float*)d_in[0];
  const float* ref_t = (const float*)d_in[1];
  const float* m1_data = (const float*)d_in[2];
  const float* m1_t = (const float*)d_in[3];
  const float* m2_data = (const float*)d_in[4];
  const float* m2_t = (const float*)d_in[5];
  const float* m3_data = (const float*)d_in[6];
  const float* m3_t = (const float*)d_in[7];
  const float* Wq = (const float*)d_in[8];
  const float* Wk1 = (const float*)d_in[9];
  const float* bk1 = (const float*)d_in[10];
  const float* Wv1 = (const float*)d_in[11];
  const float* bv1 = (const float*)d_in[12];
  const float* lt1 = (const float*)d_in[13];
  const float* Wk2 = (const float*)d_in[14];
  const float* bk2 = (const float*)d_in[15];
  const float* Wv2 = (const float*)d_in[16];
  const float* bv2 = (const float*)d_in[17];
  const float* lt2 = (const float*)d_in[18];
  const float* Wk3 = (const float*)d_in[19];
  const float* bk3 = (const float*)d_in[20];
  const float* Wv3 = (const float*)d_in[21];
  const float* bv3 = (const float*)d_in[22];
  const float* lt3 = (const float*)d_in[23];

  float* ws = (float*)d_ws;
  float* Vw = ws;                  // V_SZ
  float* Xw = Vw + V_SZ;           // X_SZ
  float* Aq = Xw + X_SZ;           // A_SZ
  float* Gq = Aq + A_SZ;           // A_SZ
  float* Yacc = Gq + A_SZ;         // Y_SZ
  float* Zacc = Yacc + Y_SZ;       // Z_SZ
  int* Cq = (int*)(Zacc + Z_SZ);   // A_SZ ints

  // zero the atomic accumulators (Yacc..Zacc contiguous)
  hipMemsetAsync(Yacc, 0, (size_t)(Y_SZ + Z_SZ) * sizeof(float), stream);

  mm_prep_qk<<<dim3((N * T) / 256), dim3(256), 0, stream>>>(
      ref_data, ref_t, m1_t, m2_t, m3_t, Wq,
      Wk1, bk1, lt1, Wk2, bk2, lt2, Wk3, bk3, lt3, Aq, Gq, Cq);
  mm_prep_v<<<dim3((3 * N * L) / 4), dim3(256), 0, stream>>>(
      m1_data, m2_data, m3_data, Wv1, bv1, Wv2, bv2, Wv3, bv3, Vw, Xw);
  mm_attn_main<<<dim3(3 * N * (T / TT) * SPLIT), dim3(256), 0, stream>>>(
      Vw, Xw, Aq, Gq, Cq, Yacc, Zacc);
  mm_finalize<<<dim3((3 * N * T * DV) / 256), dim3(256), 0, stream>>>(
      Yacc, Zacc, Cq, (float*)d_out);
}

// Round 3
// 220.324 us; speedup vs baseline: 1.2464x; 1.2338x over previous
//
#include <hip/hip_runtime.h>

namespace {

typedef unsigned int uint;
typedef unsigned short ushort_t;
typedef __attribute__((ext_vector_type(8))) short bf16x8;
typedef __attribute__((ext_vector_type(4))) float f32x4;

constexpr int N = 4, T = 2048, L = 2048;
constexpr int DQIN = 32, DQK = 64;
constexpr int TT = 64;           // t-rows per block (4 waves x 16 rows)
constexpr int SPLIT = 2;         // l-dimension split
constexpr int LSEG = L / SPLIT;  // 1024

// workspace layout (float-sized slots); total ~13.0 MB
constexpr int VH_SZ = 3 * N * 64 * L / 2;  // ushort array, as float slots
constexpr int X_SZ = 3 * N * L;
constexpr int A_SZ = 3 * N * T;
constexpr int Y_SZ = 3 * N * T * 64;
constexpr int Z_SZ = 3 * N * T;

union PK8 { int i[4]; bf16x8 s; };

// =================== fused prep kernel ===================
// blocks [0,32): Q->a,g scalars; [32,128): binary searches -> Cq; [128,512): V transform
__global__ __launch_bounds__(256) void mm_prep(
    const float* __restrict__ ref_data, const float* __restrict__ ref_t,
    const float* __restrict__ d1, const float* __restrict__ t1,
    const float* __restrict__ d2, const float* __restrict__ t2,
    const float* __restrict__ d3, const float* __restrict__ t3,
    const float* __restrict__ Wq,
    const float* __restrict__ Wk1, const float* __restrict__ bk1,
    const float* __restrict__ Wv1, const float* __restrict__ bv1, const float* __restrict__ lt1,
    const float* __restrict__ Wk2, const float* __restrict__ bk2,
    const float* __restrict__ Wv2, const float* __restrict__ bv2, const float* __restrict__ lt2,
    const float* __restrict__ Wk3, const float* __restrict__ bk3,
    const float* __restrict__ Wv3, const float* __restrict__ bv3, const float* __restrict__ lt3,
    float* __restrict__ Aq, float* __restrict__ Gq, int* __restrict__ Cq,
    ushort_t* __restrict__ Vhi, ushort_t* __restrict__ Vlo, float* __restrict__ X) {
  const int b = blockIdx.x;
  const int tid = threadIdx.x;

  if (b < 32) {
    // ---- Q path: a,g per (n,t,modality) ----
    __shared__ float sWq[DQIN * DQK];
    __shared__ float sWk[3][DQK];
    __shared__ float sbk[3][DQK];
    for (int i = tid; i < DQIN * DQK; i += 256) sWq[i] = Wq[i];
    if (tid < DQK) {
      sWk[0][tid] = Wk1[tid]; sWk[1][tid] = Wk2[tid]; sWk[2][tid] = Wk3[tid];
      sbk[0][tid] = bk1[tid]; sbk[1][tid] = bk2[tid]; sbk[2][tid] = bk3[tid];
    }
    __syncthreads();
    const int idx = b * 256 + tid;  // n*T + t
    float x[DQIN];
    const float* rp = ref_data + idx * DQIN;
#pragma unroll
    for (int i = 0; i < DQIN; i++) x[i] = rp[i];
    float qr[DQK];
#pragma unroll
    for (int j = 0; j < DQK; j += 4) {
      float4 acc4 = make_float4(0.f, 0.f, 0.f, 0.f);
#pragma unroll
      for (int i = 0; i < DQIN; i++) {
        const float4 w = *(const float4*)&sWq[i * DQK + j];
        acc4.x = fmaf(x[i], w.x, acc4.x);
        acc4.y = fmaf(x[i], w.y, acc4.y);
        acc4.z = fmaf(x[i], w.z, acc4.z);
        acc4.w = fmaf(x[i], w.w, acc4.w);
      }
      qr[j] = acc4.x; qr[j + 1] = acc4.y; qr[j + 2] = acc4.z; qr[j + 3] = acc4.w;
    }
    const float rs[3] = {__expf(-0.5f * lt1[0]), __expf(-0.5f * lt2[0]), __expf(-0.5f * lt3[0])};
#pragma unroll
    for (int m = 0; m < 3; m++) {
      float g = 0.f, h = 0.f;
#pragma unroll
      for (int j = 1; j < DQK; j++) {
        g = fmaf(qr[j], sWk[m][j - 1], g);
        h = fmaf(qr[j], sbk[m][j - 1], h);
      }
      g += sWk[m][DQK - 1];
      h += sbk[m][DQK - 1];
      Aq[m * (N * T) + idx] = (qr[0] - h) * rs[m];
      Gq[m * (N * T) + idx] = g * rs[m];
    }
  } else if (b < 128) {
    // ---- binary searches: c = #(tml <= rt), one thread per (m,n,t) ----
    const int sidx = (b - 32) * 256 + tid;  // 0..24575
    const int m = sidx >> 13;               // /8192
    const int nt = sidx & 8191;
    const int n = nt >> 11;                 // /T
    const float rt = ref_t[nt];
    const float* tml = ((m == 0) ? t1 : (m == 1 ? t2 : t3)) + n * L;
    int lo = 0, hi = L;
    while (lo < hi) {
      const int mid = (lo + hi) >> 1;
      if (tml[mid] <= rt) lo = mid + 1; else hi = mid;
    }
    Cq[m * 8192 + nt] = lo;
  } else {
    // ---- V transform: Vt[mn][dim][l] split bf16 hi/lo + X pack ----
    const int vb = b - 128;          // 0..383
    const int mn = vb >> 5;          // m*N+n
    const int m = mn >> 2, n = mn & 3;
    const int lseg0 = (vb & 31) * 64;
    const float* dm = (m == 0) ? d1 : (m == 1 ? d2 : d3);
    const float* Wv = (m == 0) ? Wv1 : (m == 1 ? Wv2 : Wv3);
    const float* bv = (m == 0) ? bv1 : (m == 1 ? bv2 : bv3);
    const int cdim = tid & 63;
    const int qq = tid >> 6;
    const int l0 = lseg0 + qq * 16;  // 16 consecutive l per thread

    float Wc[32];
#pragma unroll
    for (int i = 0; i < 32; i++) Wc[i] = Wv[i * 64 + cdim];
    const float bvc = bv[cdim];

    uint hi16[16], lo16[16];
#pragma unroll 4
    for (int k = 0; k < 16; k++) {
      const float* dp = dm + (size_t)(n * L + l0 + k) * 34;
      float acc = bvc;
#pragma unroll
      for (int i = 0; i < 32; i++) acc = fmaf(dp[i], Wc[i], acc);
      // RNE split: acc = hi + lo (+ ~2^-19 residual)
      uint u = __float_as_uint(acc);
      uint h = (u + 0x7fffu + ((u >> 16) & 1u)) & 0xffff0000u;
      float lo = acc - __uint_as_float(h);
      uint ul = __float_as_uint(lo);
      uint hl = (ul + 0x7fffu + ((ul >> 16) & 1u)) >> 16;
      hi16[k] = h >> 16;
      lo16[k] = hl;
    }
    int pk[8];
#pragma unroll
    for (int p = 0; p < 8; p++) pk[p] = (int)(hi16[2 * p] | (hi16[2 * p + 1] << 16));
    ushort_t* dsth = Vhi + ((size_t)(mn * 64 + cdim)) * L + l0;
    *(int4*)dsth = make_int4(pk[0], pk[1], pk[2], pk[3]);
    *(int4*)(dsth + 8) = make_int4(pk[4], pk[5], pk[6], pk[7]);
#pragma unroll
    for (int p = 0; p < 8; p++) pk[p] = (int)(lo16[2 * p] | (lo16[2 * p + 1] << 16));
    ushort_t* dstl = Vlo + ((size_t)(mn * 64 + cdim)) * L + l0;
    *(int4*)dstl = make_int4(pk[0], pk[1], pk[2], pk[3]);
    *(int4*)(dstl + 8) = make_int4(pk[4], pk[5], pk[6], pk[7]);

    if (tid < 64) {
      const int l = lseg0 + tid;
      X[mn * L + l] = dm[(size_t)(n * L + l) * 34 + 33];
    }
  }
}

// =================== main attention kernel (MFMA, no LDS, no barriers) ===================
// grid: 12 * 32 * SPLIT blocks, 4 waves each; wave = 16 t-rows x 64 dims.
__global__ __launch_bounds__(256) void mm_attn_main(
    const ushort_t* __restrict__ Vhi, const ushort_t* __restrict__ Vlo,
    const float* __restrict__ X,
    const float* __restrict__ Aq, const float* __restrict__ Gq, const int* __restrict__ Cq,
    float* __restrict__ Yacc, float* __restrict__ Zacc) {
  const int b = blockIdx.x;
  const int seg = b & (SPLIT - 1);
  const int bt = b / SPLIT;
  const int tile = bt & 31;        // T/TT = 32
  const int mn = bt >> 5;
  const int t0 = tile * TT;
  const int mnT = mn * T, mnL = mn * L;
  const int lBeg = seg * LSEG;

  const int tid = threadIdx.x;
  const int lane = tid & 63;
  const int rg = tid >> 6;
  const int q = lane >> 4;
  const int m16 = lane & 15;

  const int trow = t0 + rg * 16 + m16;
  const int c = Cq[mnT + trow];
  const int cmaxw = __shfl(c, 15, 64);  // c monotone in t -> lane 15 has wave max
  if (cmaxw <= lBeg) return;            // whole wave inactive; no barriers below

  const float a = Aq[mnT + trow];
  const float g = Gq[mnT + trow];
  const int lEnd = min(lBeg + LSEG, cmaxw);
  const int nch = (lEnd - lBeg + 63) >> 6;

  f32x4 acc[4];
#pragma unroll
  for (int ct = 0; ct < 4; ct++) acc[ct] = (f32x4){0.f, 0.f, 0.f, 0.f};
  float z = 0.f;

  const ushort_t* vh = Vhi + ((size_t)(mn * 64 + m16)) * L;
  const ushort_t* vl = Vlo + ((size_t)(mn * 64 + m16)) * L;
  const float* xp = X + mnL;

  for (int ch = 0; ch < nch; ch++) {
    const int base = lBeg + (ch << 6);
#pragma unroll
    for (int kk = 0; kk < 2; kk++) {
      const int k0 = base + kk * 32 + q * 8;
      const float4 xa = *(const float4*)&xp[k0];
      const float4 xb = *(const float4*)&xp[k0 + 4];
      const float xs[8] = {xa.x, xa.y, xa.z, xa.w, xb.x, xb.y, xb.z, xb.w};
      float w[8];
#pragma unroll
      for (int j = 0; j < 8; j++) {
        const float d = fmaf(-g, xs[j], a);
        const float e = __expf(-d * d);
        w[j] = (k0 + j < c) ? e : 0.f;
        z += w[j];
      }
      // split each w into bf16 hi+lo, pack into A fragments (layout: m=lane&15, k=q*8+j)
      PK8 ph, pl;
#pragma unroll
      for (int p = 0; p < 4; p++) {
        const uint u0 = __float_as_uint(w[2 * p]);
        const uint u1 = __float_as_uint(w[2 * p + 1]);
        const uint h0 = u0 & 0xffff0000u, h1 = u1 & 0xffff0000u;
        const float l0f = w[2 * p] - __uint_as_float(h0);
        const float l1f = w[2 * p + 1] - __uint_as_float(h1);
        ph.i[p] = (int)((h0 >> 16) | h1);
        pl.i[p] = (int)((__float_as_uint(l0f) >> 16) | (__float_as_uint(l1f) & 0xffff0000u));
      }
      const bf16x8 ahi = ph.s, alo = pl.s;
#pragma unroll
      for (int ct = 0; ct < 4; ct++) {
        const bf16x8 bhi = *(const bf16x8*)(vh + (size_t)ct * 16 * L + k0);
        const bf16x8 blo = *(const bf16x8*)(vl + (size_t)ct * 16 * L + k0);
        acc[ct] = __builtin_amdgcn_mfma_f32_16x16x32_bf16(ahi, bhi, acc[ct], 0, 0, 0);
        acc[ct] = __builtin_amdgcn_mfma_f32_16x16x32_bf16(ahi, blo, acc[ct], 0, 0, 0);
        acc[ct] = __builtin_amdgcn_mfma_f32_16x16x32_bf16(alo, bhi, acc[ct], 0, 0, 0);
      }
    }
  }

  // z: reduce across the 4 quad replicas of each row
  z += __shfl_xor(z, 16, 64);
  z += __shfl_xor(z, 32, 64);

  // C/D layout: col = lane&15 (+16*ct), row = q*4 + r (within wave's 16 rows)
  const int orow0 = t0 + rg * 16 + q * 4;
#pragma unroll
  for (int ct = 0; ct < 4; ct++) {
#pragma unroll
    for (int r = 0; r < 4; r++) {
      unsafeAtomicAdd(&Yacc[(size_t)(mnT + orow0 + r) * 64 + ct * 16 + m16], acc[ct][r]);
    }
  }
  if (lane < 16) unsafeAtomicAdd(&Zacc[mnT + t0 + rg * 16 + lane], z);
}

// =================== finalize: out = Y / (Z + (L - c)) ===================
__global__ __launch_bounds__(256) void mm_finalize(
    const float* __restrict__ Yacc, const float* __restrict__ Zacc,
    const int* __restrict__ Cq, float* __restrict__ out) {
  const int i = blockIdx.x * 256 + threadIdx.x;
  const int row = i >> 6;
  const float Z = Zacc[row] + (float)(L - Cq[row]);
  out[i] = Yacc[i] / Z;
}

}  // namespace

extern "C" void kernel_launch(void* const* d_in, const int* in_sizes, int n_in,
                              void* d_out, int out_size, void* d_ws, size_t ws_size,
                              hipStream_t stream) {
  const float* ref_data = (const float*)d_in[0];
  const float* ref_t = (const float*)d_in[1];
  const float* m1_data = (const float*)d_in[2];
  const float* m1_t = (const float*)d_in[3];
  const float* m2_data = (const float*)d_in[4];
  const float* m2_t = (const float*)d_in[5];
  const float* m3_data = (const float*)d_in[6];
  const float* m3_t = (const float*)d_in[7];
  const float* Wq = (const float*)d_in[8];
  const float* Wk1 = (const float*)d_in[9];
  const float* bk1 = (const float*)d_in[10];
  const float* Wv1 = (const float*)d_in[11];
  const float* bv1 = (const float*)d_in[12];
  const float* lt1 = (const float*)d_in[13];
  const float* Wk2 = (const float*)d_in[14];
  const float* bk2 = (const float*)d_in[15];
  const float* Wv2 = (const float*)d_in[16];
  const float* bv2 = (const float*)d_in[17];
  const float* lt2 = (const float*)d_in[18];
  const float* Wk3 = (const float*)d_in[19];
  const float* bk3 = (const float*)d_in[20];
  const float* Wv3 = (const float*)d_in[21];
  const float* bv3 = (const float*)d_in[22];
  const float* lt3 = (const float*)d_in[23];

  float* ws = (float*)d_ws;
  ushort_t* Vhi = (ushort_t*)ws;                    // VH_SZ float slots
  ushort_t* Vlo = (ushort_t*)(ws + VH_SZ);          // VH_SZ
  float* Xw = ws + 2 * VH_SZ;                       // X_SZ
  float* Aq = Xw + X_SZ;                            // A_SZ
  float* Gq = Aq + A_SZ;                            // A_SZ
  int* Cq = (int*)(Gq + A_SZ);                      // A_SZ
  float* Yacc = (float*)(Cq + A_SZ);                // Y_SZ
  float* Zacc = Yacc + Y_SZ;                        // Z_SZ

  hipMemsetAsync(Yacc, 0, (size_t)(Y_SZ + Z_SZ) * sizeof(float), stream);

  mm_prep<<<dim3(512), dim3(256), 0, stream>>>(
      ref_data, ref_t, m1_data, m1_t, m2_data, m2_t, m3_data, m3_t, Wq,
      Wk1, bk1, Wv1, bv1, lt1, Wk2, bk2, Wv2, bv2, lt2, Wk3, bk3, Wv3, bv3, lt3,
      Aq, Gq, Cq, Vhi, Vlo, Xw);
  mm_attn_main<<<dim3(12 * 32 * SPLIT), dim3(256), 0, stream>>>(
      Vhi, Vlo, Xw, Aq, Gq, Cq, Yacc, Zacc);
  mm_finalize<<<dim3((3 * N * T * 64) / 256), dim3(256), 0, stream>>>(
      Yacc, Zacc, Cq, (float*)d_out);
}

// Round 4
// 188.158 us; speedup vs baseline: 1.4595x; 1.1710x over previous
//
#include <hip/hip_runtime.h>

namespace {

typedef unsigned int uint;
typedef unsigned short ushort_t;
typedef __attribute__((ext_vector_type(8))) short bf16x8;
typedef __attribute__((ext_vector_type(4))) float f32x4;

constexpr int N = 4, T = 2048, L = 2048;
constexpr int DQIN = 32, DQK = 64;
constexpr int TT = 64;           // t-rows per block (4 waves x 16 rows)
constexpr int SPLIT = 4;         // l-dimension split
constexpr int LSEG = L / SPLIT;  // 512

// workspace layout (float-sized slots); total ~13.1 MB
constexpr int VI_SZ = 3 * N * 64 * L;  // ushort pairs: [dim row][p][hi8|lo8], as float slots (shorts/2)
constexpr int X_SZ = 3 * N * L;
constexpr int A_SZ = 3 * N * T;
constexpr int Y_SZ = 3 * N * T * 64;
constexpr int Z_SZ = 3 * N * T;

union PK8 { int i[4]; bf16x8 s; };

// =================== fused prep kernel ===================
// blocks [0,32): Q->a,g scalars; [32,128): binary searches; [128,512): V transform; [512,640): zero acc
__global__ __launch_bounds__(256) void mm_prep(
    const float* __restrict__ ref_data, const float* __restrict__ ref_t,
    const float* __restrict__ d1, const float* __restrict__ t1,
    const float* __restrict__ d2, const float* __restrict__ t2,
    const float* __restrict__ d3, const float* __restrict__ t3,
    const float* __restrict__ Wq,
    const float* __restrict__ Wk1, const float* __restrict__ bk1,
    const float* __restrict__ Wv1, const float* __restrict__ bv1, const float* __restrict__ lt1,
    const float* __restrict__ Wk2, const float* __restrict__ bk2,
    const float* __restrict__ Wv2, const float* __restrict__ bv2, const float* __restrict__ lt2,
    const float* __restrict__ Wk3, const float* __restrict__ bk3,
    const float* __restrict__ Wv3, const float* __restrict__ bv3, const float* __restrict__ lt3,
    float* __restrict__ Aq, float* __restrict__ Gq, int* __restrict__ Cq,
    ushort_t* __restrict__ VI, float* __restrict__ X, float* __restrict__ Yacc) {
  const int b = blockIdx.x;
  const int tid = threadIdx.x;

  if (b < 32) {
    // ---- Q path: a,g per (n,t,modality) ----
    __shared__ float sWq[DQIN * DQK];
    __shared__ float sWk[3][DQK];
    __shared__ float sbk[3][DQK];
    for (int i = tid; i < DQIN * DQK; i += 256) sWq[i] = Wq[i];
    if (tid < DQK) {
      sWk[0][tid] = Wk1[tid]; sWk[1][tid] = Wk2[tid]; sWk[2][tid] = Wk3[tid];
      sbk[0][tid] = bk1[tid]; sbk[1][tid] = bk2[tid]; sbk[2][tid] = bk3[tid];
    }
    __syncthreads();
    const int idx = b * 256 + tid;  // n*T + t
    float x[DQIN];
    const float* rp = ref_data + idx * DQIN;
#pragma unroll
    for (int i = 0; i < DQIN; i++) x[i] = rp[i];
    float qr[DQK];
#pragma unroll
    for (int j = 0; j < DQK; j += 4) {
      float4 acc4 = make_float4(0.f, 0.f, 0.f, 0.f);
#pragma unroll
      for (int i = 0; i < DQIN; i++) {
        const float4 w = *(const float4*)&sWq[i * DQK + j];
        acc4.x = fmaf(x[i], w.x, acc4.x);
        acc4.y = fmaf(x[i], w.y, acc4.y);
        acc4.z = fmaf(x[i], w.z, acc4.z);
        acc4.w = fmaf(x[i], w.w, acc4.w);
      }
      qr[j] = acc4.x; qr[j + 1] = acc4.y; qr[j + 2] = acc4.z; qr[j + 3] = acc4.w;
    }
    const float rs[3] = {__expf(-0.5f * lt1[0]), __expf(-0.5f * lt2[0]), __expf(-0.5f * lt3[0])};
#pragma unroll
    for (int m = 0; m < 3; m++) {
      float g = 0.f, h = 0.f;
#pragma unroll
      for (int j = 1; j < DQK; j++) {
        g = fmaf(qr[j], sWk[m][j - 1], g);
        h = fmaf(qr[j], sbk[m][j - 1], h);
      }
      g += sWk[m][DQK - 1];
      h += sbk[m][DQK - 1];
      Aq[m * (N * T) + idx] = (qr[0] - h) * rs[m];
      Gq[m * (N * T) + idx] = g * rs[m];
    }
  } else if (b < 128) {
    // ---- binary searches: c = #(tml <= rt) ----
    const int sidx = (b - 32) * 256 + tid;
    const int m = sidx >> 13;
    const int nt = sidx & 8191;
    const int n = nt >> 11;
    const float rt = ref_t[nt];
    const float* tml = ((m == 0) ? t1 : (m == 1 ? t2 : t3)) + n * L;
    int lo = 0, hi = L;
    while (lo < hi) {
      const int mid = (lo + hi) >> 1;
      if (tml[mid] <= rt) lo = mid + 1; else hi = mid;
    }
    Cq[m * 8192 + nt] = lo;
  } else if (b < 512) {
    // ---- V transform: VI[mn][dim][p]{hi8,lo8} + X pack ----
    const int vb = b - 128;          // 0..383
    const int mn = vb >> 5;          // m*N+n
    const int m = mn >> 2, n = mn & 3;
    const int lseg0 = (vb & 31) * 64;
    const float* dm = (m == 0) ? d1 : (m == 1 ? d2 : d3);
    const float* Wv = (m == 0) ? Wv1 : (m == 1 ? Wv2 : Wv3);
    const float* bv = (m == 0) ? bv1 : (m == 1 ? bv2 : bv3);
    const int cdim = tid & 63;
    const int qq = tid >> 6;
    const int l0 = lseg0 + qq * 16;  // 16 consecutive l per thread

    float Wc[32];
#pragma unroll
    for (int i = 0; i < 32; i++) Wc[i] = Wv[i * 64 + cdim];
    const float bvc = bv[cdim];

    uint hi16[16], lo16[16];
#pragma unroll 4
    for (int k = 0; k < 16; k++) {
      const float* dp = dm + (size_t)(n * L + l0 + k) * 34;
      float acc = bvc;
#pragma unroll
      for (int i = 0; i < 32; i++) acc = fmaf(dp[i], Wc[i], acc);
      uint u = __float_as_uint(acc);
      uint h = (u + 0x7fffu + ((u >> 16) & 1u)) & 0xffff0000u;
      float res = acc - __uint_as_float(h);
      uint ul = __float_as_uint(res);
      uint hl = (ul + 0x7fffu + ((ul >> 16) & 1u)) >> 16;
      hi16[k] = h >> 16;
      lo16[k] = hl;
    }
    int pkh[8], pkl[8];
#pragma unroll
    for (int p = 0; p < 8; p++) {
      pkh[p] = (int)(hi16[2 * p] | (hi16[2 * p + 1] << 16));
      pkl[p] = (int)(lo16[2 * p] | (lo16[2 * p + 1] << 16));
    }
    // layout: row = mn*64+cdim (stride 2L shorts), group p = l/8 -> 16 shorts [hi8|lo8]
    ushort_t* dst = VI + (size_t)(mn * 64 + cdim) * (2 * L) + (l0 >> 3) * 16;
    *(int4*)dst = make_int4(pkh[0], pkh[1], pkh[2], pkh[3]);
    *(int4*)(dst + 8) = make_int4(pkl[0], pkl[1], pkl[2], pkl[3]);
    *(int4*)(dst + 16) = make_int4(pkh[4], pkh[5], pkh[6], pkh[7]);
    *(int4*)(dst + 24) = make_int4(pkl[4], pkl[5], pkl[6], pkl[7]);

    if (tid < 64) {
      const int l = lseg0 + tid;
      X[mn * L + l] = dm[(size_t)(n * L + l) * 34 + 33];
    }
  } else {
    // ---- zero Yacc..Zacc (contiguous, (Y_SZ+Z_SZ)/4 float4s) ----
    float4* dst = (float4*)Yacc;
    const float4 zz = make_float4(0.f, 0.f, 0.f, 0.f);
    const int stride = 128 * 256;
    for (int i = (b - 512) * 256 + tid; i < (Y_SZ + Z_SZ) / 4; i += stride) dst[i] = zz;
  }
}

// =================== main attention kernel ===================
struct Buf {
  bf16x8 h[8];   // [kk*4+ct]
  bf16x8 l[8];
  float4 x[4];   // [kk*2+half]
};

__device__ inline void load_buf(Buf& B, const ushort_t* vbase, const float* xp, int base, int q) {
#pragma unroll
  for (int kk = 0; kk < 2; kk++) {
    const int p = ((base + kk * 32) >> 3) + q;
#pragma unroll
    for (int ct = 0; ct < 4; ct++) {
      const ushort_t* ptr = vbase + (size_t)ct * (16 * 2 * L) + p * 16;
      B.h[kk * 4 + ct] = *(const bf16x8*)ptr;
      B.l[kk * 4 + ct] = *(const bf16x8*)(ptr + 8);
    }
    const int k0 = base + kk * 32 + q * 8;
    B.x[kk * 2] = *(const float4*)&xp[k0];
    B.x[kk * 2 + 1] = *(const float4*)&xp[k0 + 4];
  }
}

__device__ inline void step(const Buf& B, int base, int q, int c, float a, float g,
                            f32x4 acc[4], float& z) {
#pragma unroll
  for (int kk = 0; kk < 2; kk++) {
    const int k0 = base + kk * 32 + q * 8;
    const float4 xa = B.x[kk * 2], xb = B.x[kk * 2 + 1];
    const float xs[8] = {xa.x, xa.y, xa.z, xa.w, xb.x, xb.y, xb.z, xb.w};
    float w[8];
#pragma unroll
    for (int j = 0; j < 8; j++) {
      const float d = fmaf(-g, xs[j], a);
      const float e = __expf(-d * d);
      w[j] = (k0 + j < c) ? e : 0.f;
      z += w[j];
    }
    PK8 ph, pl;
#pragma unroll
    for (int p2 = 0; p2 < 4; p2++) {
      const uint u0 = __float_as_uint(w[2 * p2]);
      const uint u1 = __float_as_uint(w[2 * p2 + 1]);
      const uint h0 = u0 & 0xffff0000u, h1 = u1 & 0xffff0000u;
      const float l0f = w[2 * p2] - __uint_as_float(h0);
      const float l1f = w[2 * p2 + 1] - __uint_as_float(h1);
      ph.i[p2] = (int)((h0 >> 16) | h1);
      pl.i[p2] = (int)((__float_as_uint(l0f) >> 16) | (__float_as_uint(l1f) & 0xffff0000u));
    }
    const bf16x8 ahi = ph.s, alo = pl.s;
#pragma unroll
    for (int ct = 0; ct < 4; ct++) {
      acc[ct] = __builtin_amdgcn_mfma_f32_16x16x32_bf16(ahi, B.h[kk * 4 + ct], acc[ct], 0, 0, 0);
      acc[ct] = __builtin_amdgcn_mfma_f32_16x16x32_bf16(ahi, B.l[kk * 4 + ct], acc[ct], 0, 0, 0);
      acc[ct] = __builtin_amdgcn_mfma_f32_16x16x32_bf16(alo, B.h[kk * 4 + ct], acc[ct], 0, 0, 0);
    }
  }
}

// grid: 12*32*SPLIT blocks (mn = b%12 for XCD L2 locality), 4 waves; wave = 16 t x 64 dims.
__global__ __launch_bounds__(256) void mm_attn_main(
    const ushort_t* __restrict__ VI, const float* __restrict__ X,
    const float* __restrict__ Aq, const float* __restrict__ Gq, const int* __restrict__ Cq,
    float* __restrict__ Yacc, float* __restrict__ Zacc) {
  const int b = blockIdx.x;
  const int mn = b % 12;
  const int r = b / 12;           // 0..127
  const int tile = r >> 2;        // 0..31
  const int seg = r & 3;
  const int t0 = tile * TT;
  const int mnT = mn * T, mnL = mn * L;
  const int lBeg = seg * LSEG;

  const int tid = threadIdx.x;
  const int lane = tid & 63;
  const int rg = tid >> 6;
  const int q = lane >> 4;
  const int m16 = lane & 15;

  const int trow = t0 + rg * 16 + m16;
  const int c = Cq[mnT + trow];
  const int cmaxw = __shfl(c, 15, 64);  // c monotone in t
  if (cmaxw <= lBeg) return;            // no barriers in this kernel

  const float a = Aq[mnT + trow];
  const float g = Gq[mnT + trow];
  const int lEnd = min(lBeg + LSEG, cmaxw);
  const int nch = (lEnd - lBeg + 63) >> 6;

  f32x4 acc[4];
#pragma unroll
  for (int ct = 0; ct < 4; ct++) acc[ct] = (f32x4){0.f, 0.f, 0.f, 0.f};
  float z = 0.f;

  const ushort_t* vbase = VI + (size_t)(mn * 64 + m16) * (2 * L);
  const float* xp = X + mnL;

  // explicit double-buffered register pipeline: loads for chunk k+1 in flight during step(k)
  Buf b0, b1;
  int base = lBeg, ch = 0;
  load_buf(b0, vbase, xp, base, q);
  for (; ch + 2 <= nch; ch += 2, base += 128) {
    load_buf(b1, vbase, xp, base + 64, q);
    step(b0, base, q, c, a, g, acc, z);
    if (ch + 2 < nch) load_buf(b0, vbase, xp, base + 128, q);
    step(b1, base + 64, q, c, a, g, acc, z);
  }
  if (ch < nch) step(b0, base, q, c, a, g, acc, z);

  z += __shfl_xor(z, 16, 64);
  z += __shfl_xor(z, 32, 64);

  const int orow0 = t0 + rg * 16 + q * 4;
#pragma unroll
  for (int ct = 0; ct < 4; ct++) {
#pragma unroll
    for (int rr = 0; rr < 4; rr++) {
      unsafeAtomicAdd(&Yacc[(size_t)(mnT + orow0 + rr) * 64 + ct * 16 + m16], acc[ct][rr]);
    }
  }
  if (lane < 16) unsafeAtomicAdd(&Zacc[mnT + t0 + rg * 16 + lane], z);
}

// =================== finalize: out = Y / (Z + (L - c)), float4 ===================
__global__ __launch_bounds__(256) void mm_finalize(
    const float4* __restrict__ Y4, const float* __restrict__ Zacc,
    const int* __restrict__ Cq, float4* __restrict__ out4) {
  const int i = blockIdx.x * 256 + threadIdx.x;  // over 3*N*T*16 float4s
  const int row = i >> 4;
  const float Zr = Zacc[row] + (float)(L - Cq[row]);
  const float inv = 1.0f / Zr;
  const float4 y = Y4[i];
  out4[i] = make_float4(y.x * inv, y.y * inv, y.z * inv, y.w * inv);
}

}  // namespace

extern "C" void kernel_launch(void* const* d_in, const int* in_sizes, int n_in,
                              void* d_out, int out_size, void* d_ws, size_t ws_size,
                              hipStream_t stream) {
  const float* ref_data = (const float*)d_in[0];
  const float* ref_t = (const float*)d_in[1];
  const float* m1_data = (const float*)d_in[2];
  const float* m1_t = (const float*)d_in[3];
  const float* m2_data = (const float*)d_in[4];
  const float* m2_t = (const float*)d_in[5];
  const float* m3_data = (const float*)d_in[6];
  const float* m3_t = (const float*)d_in[7];
  const float* Wq = (const float*)d_in[8];
  const float* Wk1 = (const float*)d_in[9];
  const float* bk1 = (const float*)d_in[10];
  const float* Wv1 = (const float*)d_in[11];
  const float* bv1 = (const float*)d_in[12];
  const float* lt1 = (const float*)d_in[13];
  const float* Wk2 = (const float*)d_in[14];
  const float* bk2 = (const float*)d_in[15];
  const float* Wv2 = (const float*)d_in[16];
  const float* bv2 = (const float*)d_in[17];
  const float* lt2 = (const float*)d_in[18];
  const float* Wk3 = (const float*)d_in[19];
  const float* bk3 = (const float*)d_in[20];
  const float* Wv3 = (const float*)d_in[21];
  const float* bv3 = (const float*)d_in[22];
  const float* lt3 = (const float*)d_in[23];

  float* ws = (float*)d_ws;
  ushort_t* VI = (ushort_t*)ws;                 // VI_SZ float slots
  float* Xw = ws + VI_SZ;                       // X_SZ
  float* Aq = Xw + X_SZ;                        // A_SZ
  float* Gq = Aq + A_SZ;                        // A_SZ
  int* Cq = (int*)(Gq + A_SZ);                  // A_SZ
  float* Yacc = (float*)(Cq + A_SZ);            // Y_SZ
  float* Zacc = Yacc + Y_SZ;                    // Z_SZ

  mm_prep<<<dim3(640), dim3(256), 0, stream>>>(
      ref_data, ref_t, m1_data, m1_t, m2_data, m2_t, m3_data, m3_t, Wq,
      Wk1, bk1, Wv1, bv1, lt1, Wk2, bk2, Wv2, bv2, lt2, Wk3, bk3, Wv3, bv3, lt3,
      Aq, Gq, Cq, VI, Xw, Yacc);
  mm_attn_main<<<dim3(12 * 32 * SPLIT), dim3(256), 0, stream>>>(
      VI, Xw, Aq, Gq, Cq, Yacc, Zacc);
  mm_finalize<<<dim3((3 * N * T * 16) / 256), dim3(256), 0, stream>>>(
      (const float4*)Yacc, Zacc, Cq, (float4*)d_out);
}